// Round 4
// baseline (360.923 us; speedup 1.0000x reference)
//
#include <hip/hip_runtime.h>

#define B_   8
#define H_   112
#define W_   112
#define HW_  12544
#define C_   128
#define NH_  4
#define HD_  32
#define KK_  49
#define N_   100352
#define SCALE_ 0.17677669529663687f   // 1/sqrt(32)

typedef __attribute__((ext_vector_type(8))) short short8;
typedef __attribute__((ext_vector_type(4))) float floatx4;

__device__ __forceinline__ unsigned short f2bf(float f) {
  unsigned u = __float_as_uint(f);
  return (unsigned short)((u + 0x7fffu + ((u >> 16) & 1u)) >> 16);
}
__device__ __forceinline__ float bf2f(unsigned short h) {
  return __uint_as_float(((unsigned)h) << 16);
}

// ---------------- K0: weight prep ----------------
// qkv_w (384x128, [oc][c]) and proj_w (128x128, [oc][c]) -> bf16 hi/lo splits.
// Row-major is already MFMA A-fragment order (lane m16 = oc row, k contiguous).
__global__ __launch_bounds__(256) void k_wt(
    const float* __restrict__ qw, const float* __restrict__ pw,
    unsigned short* __restrict__ wh, unsigned short* __restrict__ wl,
    unsigned short* __restrict__ pwh, unsigned short* __restrict__ pwl)
{
  const int idx = blockIdx.x * 256 + threadIdx.x;
  if (idx < 384 * 128) {
    const float v = qw[idx];
    const unsigned short h = f2bf(v);
    wh[idx] = h;
    wl[idx] = f2bf(v - bf2f(h));
  }
  if (idx < 128 * 128) {
    const float v = pw[idx];
    const unsigned short h = f2bf(v);
    pwh[idx] = h;
    pwl[idx] = f2bf(v - bf2f(h));
  }
}

// ---------------- K1: QKV via split-bf16 MFMA + q.k dot + v store ----------
// Block = 64 px, 4 waves; wave w = head w. Staging: global float4 pairs ->
// register bf16 split -> packed b32 LDS writes (no fp32 xs[] -> 34 KB LDS,
// 4 blocks/CU). Y ~ xh*wh + xh*wl + xl*wh.
__global__ __launch_bounds__(256, 4) void k_qkv(
    const float* __restrict__ x, const unsigned short* __restrict__ wh,
    const unsigned short* __restrict__ wl, const float* __restrict__ qb,
    float* __restrict__ vbuf, float* __restrict__ dotbuf)
{
  __shared__ __align__(16) unsigned short xh[64 * 136];  // [px][c] bf16-hi
  __shared__ __align__(16) unsigned short xl[64 * 136];  // [px][c] bf16-lo
  const int tid = threadIdx.x;
  const int b   = blockIdx.x / 196;
  const int hw0 = (blockIdx.x % 196) * 64;

  { // stage: thread = (c,c+1) x 4 px; coalesced float4 loads, packed writes
    const float* xb = x + (size_t)b * C_ * HW_ + hw0;
    const int p4 = (tid & 15) * 4;
#pragma unroll
    for (int rep = 0; rep < 4; ++rep) {
      const int c = ((tid >> 4) + rep * 16) * 2;
      const float4 fa = *(const float4*)(xb + (size_t)c * HW_ + p4);
      const float4 fb = *(const float4*)(xb + (size_t)(c + 1) * HW_ + p4);
      const float va[4] = {fa.x, fa.y, fa.z, fa.w};
      const float vb[4] = {fb.x, fb.y, fb.z, fb.w};
#pragma unroll
      for (int i = 0; i < 4; ++i) {
        const unsigned short ha = f2bf(va[i]), hb = f2bf(vb[i]);
        const unsigned short la = f2bf(va[i] - bf2f(ha));
        const unsigned short lb = f2bf(vb[i] - bf2f(hb));
        *(unsigned*)(xh + (p4 + i) * 136 + c) = (unsigned)ha | ((unsigned)hb << 16);
        *(unsigned*)(xl + (p4 + i) * 136 + c) = (unsigned)la | ((unsigned)lb << 16);
      }
    }
  }
  __syncthreads();

  const int w    = __builtin_amdgcn_readfirstlane(tid >> 6);
  const int l    = tid & 63;
  const int m16  = l & 15;
  const int quad = l >> 4;

  int ocbase[6];
#pragma unroll
  for (int g = 0; g < 6; ++g) ocbase[g] = (g >> 1) * 128 + w * 32 + (g & 1) * 16;

  floatx4 acc[6][4];
#pragma unroll
  for (int g = 0; g < 6; ++g)
#pragma unroll
    for (int p = 0; p < 4; ++p) acc[g][p] = (floatx4){0.f, 0.f, 0.f, 0.f};

  for (int ks = 0; ks < 4; ++ks) {
    short8 bh[4], bl[4];
#pragma unroll
    for (int p = 0; p < 4; ++p) {
      const int off = (p * 16 + m16) * 136 + ks * 32 + quad * 8;
      bh[p] = *(const short8*)(xh + off);
      bl[p] = *(const short8*)(xl + off);
    }
#pragma unroll
    for (int g = 0; g < 6; ++g) {
      const size_t woff = (size_t)(ocbase[g] + m16) * C_ + ks * 32 + quad * 8;
      const short8 ah = *(const short8*)(wh + woff);
      const short8 al = *(const short8*)(wl + woff);
#pragma unroll
      for (int p = 0; p < 4; ++p) {
        acc[g][p] = __builtin_amdgcn_mfma_f32_16x16x32_bf16(ah, bh[p], acc[g][p], 0, 0, 0);
        acc[g][p] = __builtin_amdgcn_mfma_f32_16x16x32_bf16(ah, bl[p], acc[g][p], 0, 0, 0);
        acc[g][p] = __builtin_amdgcn_mfma_f32_16x16x32_bf16(al, bh[p], acc[g][p], 0, 0, 0);
      }
    }
  }

  float bias[6][4];
#pragma unroll
  for (int g = 0; g < 6; ++g)
#pragma unroll
    for (int r = 0; r < 4; ++r) bias[g][r] = qb[ocbase[g] + quad * 4 + r];

  const size_t dbase = (size_t)(b * NH_ + w) * HW_ + hw0;

#pragma unroll
  for (int p = 0; p < 4; ++p) {
    float part = 0.f;
#pragma unroll
    for (int t = 0; t < 2; ++t)
#pragma unroll
      for (int r = 0; r < 4; ++r)
        part += (acc[t][p][r] + bias[t][r]) * (acc[2 + t][p][r] + bias[2 + t][r]);
    part += __shfl_xor(part, 16);
    part += __shfl_xor(part, 32);
    if (l < 16) dotbuf[dbase + p * 16 + l] = part * SCALE_;
  }

#pragma unroll
  for (int t = 0; t < 2; ++t) {
#pragma unroll
    for (int p = 0; p < 4; ++p) {
      floatx4 vv = acc[4 + t][p];
#pragma unroll
      for (int r = 0; r < 4; ++r) vv[r] += bias[4 + t][r];
      float* vp = vbuf + (dbase + p * 16 + m16) * HD_ + t * 16 + quad * 4;
      *(floatx4*)vp = vv;
    }
  }
}

// ---------------- K2: neighborhood softmax + A*V -> bf16 hi/lo out ---------
__global__ __launch_bounds__(256) void k_attn(
    const float* __restrict__ vbuf, const float* __restrict__ dotbuf,
    const float* __restrict__ rpb, unsigned short* __restrict__ ao_h,
    unsigned short* __restrict__ ao_l)
{
  __shared__ __align__(16) float at[KK_ * 256];
  __shared__ float rsum[256];
  const int tid  = threadIdx.x;
  const int blk  = blockIdx.x;
  const int head = blk / 392;
  const int rem  = blk % 392;
  const int b    = rem / 49;
  const int t49  = rem % 49;
  const int r0 = (t49 / 7) * 16;
  const int w0 = (t49 % 7) * 16;
  const float* dptr = dotbuf + (size_t)(b * NH_ + head) * HW_;

  {
    const int r = tid >> 4, wv = tid & 15;
    const int gh = r0 + r, gw = w0 + wv;
    float logit[KK_];
    float m = -1e30f;
#pragma unroll
    for (int i = 0; i < 7; ++i) {
      int hr = gh + i; if (hr >= H_) hr -= H_;
      const float* drow = dptr + hr * W_;
#pragma unroll
      for (int j = 0; j < 7; ++j) {
        int wc = gw + j; if (wc >= W_) wc -= W_;
        const float l = drow[wc] + rpb[head * KK_ + i * 7 + j];
        logit[i * 7 + j] = l;
        m = fmaxf(m, l);
      }
    }
    float s = 0.f;
#pragma unroll
    for (int o = 0; o < KK_; ++o) {
      const float e = __expf(logit[o] - m);
      s += e;
      at[o * 256 + tid] = e;
    }
    rsum[tid] = 1.0f / s;
  }
  __syncthreads();

  const int c4  = tid & 7;
  const int seg = tid >> 3;
  const int r   = seg >> 1;
  const int sx  = (seg & 1) * 8;
  const int gh  = r0 + r;
  const int pxb = r * 16 + sx;
  const float* vb = vbuf + (size_t)(b * NH_ + head) * HW_ * HD_ + c4 * 4;

  float4 acc[8];
#pragma unroll
  for (int xx = 0; xx < 8; ++xx) acc[xx] = make_float4(0.f, 0.f, 0.f, 0.f);

  for (int i = 0; i < 7; ++i) {
    int hr = gh + i; if (hr >= H_) hr -= H_;
    float4 win[14];
#pragma unroll
    for (int t = 0; t < 14; ++t) {
      int wc = w0 + sx + t; if (wc >= W_) wc -= W_;
      win[t] = *(const float4*)(vb + ((size_t)hr * W_ + wc) * HD_);
    }
#pragma unroll
    for (int j = 0; j < 7; ++j) {
      const float* arow = at + (i * 7 + j) * 256 + pxb;
      const float4 a0 = *(const float4*)arow;
      const float4 a1 = *(const float4*)(arow + 4);
      const float aw[8] = {a0.x, a0.y, a0.z, a0.w, a1.x, a1.y, a1.z, a1.w};
#pragma unroll
      for (int xx = 0; xx < 8; ++xx) {
        acc[xx].x = fmaf(aw[xx], win[xx + j].x, acc[xx].x);
        acc[xx].y = fmaf(aw[xx], win[xx + j].y, acc[xx].y);
        acc[xx].z = fmaf(aw[xx], win[xx + j].z, acc[xx].z);
        acc[xx].w = fmaf(aw[xx], win[xx + j].w, acc[xx].w);
      }
    }
  }

  // out: (B,HW,C) bf16 hi/lo planes, c = head*32 + c4*4 .. +3 (8B aligned)
  const size_t obase =
      ((size_t)b * HW_ + (size_t)gh * W_ + (w0 + sx)) * C_ + head * HD_ + c4 * 4;
#pragma unroll
  for (int xx = 0; xx < 8; ++xx) {
    const float rs = rsum[pxb + xx];
    const float o0 = acc[xx].x * rs, o1 = acc[xx].y * rs;
    const float o2 = acc[xx].z * rs, o3 = acc[xx].w * rs;
    const unsigned short h0 = f2bf(o0), h1 = f2bf(o1), h2 = f2bf(o2), h3 = f2bf(o3);
    ushort4 hv; hv.x = h0; hv.y = h1; hv.z = h2; hv.w = h3;
    ushort4 lv;
    lv.x = f2bf(o0 - bf2f(h0)); lv.y = f2bf(o1 - bf2f(h1));
    lv.z = f2bf(o2 - bf2f(h2)); lv.w = f2bf(o3 - bf2f(h3));
    *(ushort4*)(ao_h + obase + (size_t)xx * C_) = hv;
    *(ushort4*)(ao_l + obase + (size_t)xx * C_) = lv;
  }
}

// ---------------- K3: proj via split-bf16 MFMA + NHWC -> NCHW --------------
// Block = 64 px, 4 waves; wave w -> oc in [w*32, w*32+32). No LDS, no barrier:
// A (weights) and B (attn-out) frags straight from global/L2.
__global__ __launch_bounds__(256, 4) void k_proj(
    const unsigned short* __restrict__ ao_h, const unsigned short* __restrict__ ao_l,
    const unsigned short* __restrict__ pwh, const unsigned short* __restrict__ pwl,
    const float* __restrict__ pb, float* __restrict__ out)
{
  const int tid = threadIdx.x;
  const int b   = blockIdx.x / 196;
  const int hw0 = (blockIdx.x % 196) * 64;
  const int w    = __builtin_amdgcn_readfirstlane(tid >> 6);
  const int l    = tid & 63;
  const int m16  = l & 15;
  const int quad = l >> 4;

  floatx4 acc[2][4];
#pragma unroll
  for (int t = 0; t < 2; ++t)
#pragma unroll
    for (int p = 0; p < 4; ++p) acc[t][p] = (floatx4){0.f, 0.f, 0.f, 0.f};

  const size_t pxbase = (size_t)b * HW_ + hw0;

  for (int ks = 0; ks < 4; ++ks) {
    short8 bh[4], bl[4];
#pragma unroll
    for (int p = 0; p < 4; ++p) {
      const size_t off = (pxbase + p * 16 + m16) * C_ + ks * 32 + quad * 8;
      bh[p] = *(const short8*)(ao_h + off);
      bl[p] = *(const short8*)(ao_l + off);
    }
#pragma unroll
    for (int t = 0; t < 2; ++t) {
      const size_t woff = (size_t)(w * 32 + t * 16 + m16) * C_ + ks * 32 + quad * 8;
      const short8 wah = *(const short8*)(pwh + woff);
      const short8 wal = *(const short8*)(pwl + woff);
#pragma unroll
      for (int p = 0; p < 4; ++p) {
        acc[t][p] = __builtin_amdgcn_mfma_f32_16x16x32_bf16(wah, bh[p], acc[t][p], 0, 0, 0);
        acc[t][p] = __builtin_amdgcn_mfma_f32_16x16x32_bf16(wah, bl[p], acc[t][p], 0, 0, 0);
        acc[t][p] = __builtin_amdgcn_mfma_f32_16x16x32_bf16(wal, bh[p], acc[t][p], 0, 0, 0);
      }
    }
  }

#pragma unroll
  for (int t = 0; t < 2; ++t) {
    float bias[4];
#pragma unroll
    for (int r = 0; r < 4; ++r) bias[r] = pb[w * 32 + t * 16 + quad * 4 + r];
#pragma unroll
    for (int p = 0; p < 4; ++p) {
#pragma unroll
      for (int r = 0; r < 4; ++r) {
        const int oc = w * 32 + t * 16 + quad * 4 + r;
        out[(size_t)b * C_ * HW_ + (size_t)oc * HW_ + hw0 + p * 16 + m16] =
            acc[t][p][r] + bias[r];
      }
    }
  }
}

extern "C" void kernel_launch(void* const* d_in, const int* in_sizes, int n_in,
                              void* d_out, int out_size, void* d_ws, size_t ws_size,
                              hipStream_t stream) {
  const float* x   = (const float*)d_in[0];
  const float* qw  = (const float*)d_in[1];
  const float* qb  = (const float*)d_in[2];
  const float* rpb = (const float*)d_in[3];
  const float* pw  = (const float*)d_in[4];
  const float* pb  = (const float*)d_in[5];
  float* out = (float*)d_out;

  float* vbuf = (float*)d_ws;                          // N*C fp32 (51.4 MB)
  float* dotb = vbuf + (size_t)N_ * C_;                // N*NH fp32 (1.6 MB)
  unsigned short* ao_h = (unsigned short*)(dotb + (size_t)N_ * NH_);  // N*C bf16
  unsigned short* ao_l = ao_h + (size_t)N_ * C_;       // N*C bf16
  unsigned short* wh   = ao_l + (size_t)N_ * C_;       // 384*128 bf16
  unsigned short* wl   = wh + 384 * C_;
  unsigned short* pwh  = wl + 384 * C_;                // 128*128 bf16
  unsigned short* pwl  = pwh + C_ * C_;

  hipLaunchKernelGGL(k_wt,   dim3(192), dim3(256), 0, stream, qw, pw, wh, wl, pwh, pwl);
  hipLaunchKernelGGL(k_qkv,  dim3(N_ / 64), dim3(256), 0, stream, x, wh, wl, qb, vbuf, dotb);
  hipLaunchKernelGGL(k_attn, dim3(NH_ * B_ * 49), dim3(256), 0, stream, vbuf, dotb, rpb, ao_h, ao_l);
  hipLaunchKernelGGL(k_proj, dim3(N_ / 64), dim3(256), 0, stream, ao_h, ao_l, pwh, pwl, pb, out);
}

// Round 5
// 250.518 us; speedup vs baseline: 1.4407x; 1.4407x over previous
//
#include <hip/hip_runtime.h>

#define B_   8
#define H_   112
#define W_   112
#define HW_  12544
#define C_   128
#define NH_  4
#define HD_  32
#define KK_  49
#define N_   100352
#define SCALE_ 0.17677669529663687f   // 1/sqrt(32)

typedef __attribute__((ext_vector_type(8))) short short8;
typedef __attribute__((ext_vector_type(4))) float floatx4;

__device__ __forceinline__ unsigned short f2bf(float f) {
  unsigned u = __float_as_uint(f);
  return (unsigned short)((u + 0x7fffu + ((u >> 16) & 1u)) >> 16);
}
__device__ __forceinline__ float bf2f(unsigned short h) {
  return __uint_as_float(((unsigned)h) << 16);
}

// ---------------- K0: weight prep ----------------
// qkv_w (384x128, [oc][c]) and proj_w (128x128, [oc][c]) -> bf16 hi/lo splits.
// Row-major is already MFMA A-fragment order (lane m16 = oc row, k contiguous).
__global__ __launch_bounds__(256) void k_wt(
    const float* __restrict__ qw, const float* __restrict__ pw,
    unsigned short* __restrict__ wh, unsigned short* __restrict__ wl,
    unsigned short* __restrict__ pwh, unsigned short* __restrict__ pwl)
{
  const int idx = blockIdx.x * 256 + threadIdx.x;
  if (idx < 384 * 128) {
    const float v = qw[idx];
    const unsigned short h = f2bf(v);
    wh[idx] = h;
    wl[idx] = f2bf(v - bf2f(h));
  }
  if (idx < 128 * 128) {
    const float v = pw[idx];
    const unsigned short h = f2bf(v);
    pwh[idx] = h;
    pwl[idx] = f2bf(v - bf2f(h));
  }
}

// ---------------- K1: QKV via split-bf16 MFMA + q.k dot + v store ----------
// Block = 64 px, 4 waves; wave w = head w. Staging: global float4 pairs ->
// register bf16 split -> packed b32 LDS writes. LDS 34.8 KB -> 4 blocks/CU.
// __launch_bounds__(256,2): do NOT clamp tighter — (256,4) caps the unified
// VGPR/AGPR file at 128 and spills (R4: 8x HBM amplification, 3x regression).
__global__ __launch_bounds__(256, 2) void k_qkv(
    const float* __restrict__ x, const unsigned short* __restrict__ wh,
    const unsigned short* __restrict__ wl, const float* __restrict__ qb,
    float* __restrict__ vbuf, float* __restrict__ dotbuf)
{
  __shared__ __align__(16) unsigned short xh[64 * 136];  // [px][c] bf16-hi
  __shared__ __align__(16) unsigned short xl[64 * 136];  // [px][c] bf16-lo
  const int tid = threadIdx.x;
  const int b   = blockIdx.x / 196;
  const int hw0 = (blockIdx.x % 196) * 64;

  { // stage: thread = (c,c+1) x 4 px; coalesced float4 loads, packed writes
    const float* xb = x + (size_t)b * C_ * HW_ + hw0;
    const int p4 = (tid & 15) * 4;
#pragma unroll
    for (int rep = 0; rep < 4; ++rep) {
      const int c = ((tid >> 4) + rep * 16) * 2;
      const float4 fa = *(const float4*)(xb + (size_t)c * HW_ + p4);
      const float4 fb = *(const float4*)(xb + (size_t)(c + 1) * HW_ + p4);
      const float va[4] = {fa.x, fa.y, fa.z, fa.w};
      const float vb[4] = {fb.x, fb.y, fb.z, fb.w};
#pragma unroll
      for (int i = 0; i < 4; ++i) {
        const unsigned short ha = f2bf(va[i]), hb = f2bf(vb[i]);
        const unsigned short la = f2bf(va[i] - bf2f(ha));
        const unsigned short lb = f2bf(vb[i] - bf2f(hb));
        *(unsigned*)(xh + (p4 + i) * 136 + c) = (unsigned)ha | ((unsigned)hb << 16);
        *(unsigned*)(xl + (p4 + i) * 136 + c) = (unsigned)la | ((unsigned)lb << 16);
      }
    }
  }
  __syncthreads();

  const int w    = __builtin_amdgcn_readfirstlane(tid >> 6);
  const int l    = tid & 63;
  const int m16  = l & 15;
  const int quad = l >> 4;

  int ocbase[6];
#pragma unroll
  for (int g = 0; g < 6; ++g) ocbase[g] = (g >> 1) * 128 + w * 32 + (g & 1) * 16;

  floatx4 acc[6][4];
#pragma unroll
  for (int g = 0; g < 6; ++g)
#pragma unroll
    for (int p = 0; p < 4; ++p) acc[g][p] = (floatx4){0.f, 0.f, 0.f, 0.f};

  for (int ks = 0; ks < 4; ++ks) {
    short8 bh[4], bl[4];
#pragma unroll
    for (int p = 0; p < 4; ++p) {
      const int off = (p * 16 + m16) * 136 + ks * 32 + quad * 8;
      bh[p] = *(const short8*)(xh + off);
      bl[p] = *(const short8*)(xl + off);
    }
#pragma unroll
    for (int g = 0; g < 6; ++g) {
      const size_t woff = (size_t)(ocbase[g] + m16) * C_ + ks * 32 + quad * 8;
      const short8 ah = *(const short8*)(wh + woff);
      const short8 al = *(const short8*)(wl + woff);
#pragma unroll
      for (int p = 0; p < 4; ++p) {
        acc[g][p] = __builtin_amdgcn_mfma_f32_16x16x32_bf16(ah, bh[p], acc[g][p], 0, 0, 0);
        acc[g][p] = __builtin_amdgcn_mfma_f32_16x16x32_bf16(ah, bl[p], acc[g][p], 0, 0, 0);
        acc[g][p] = __builtin_amdgcn_mfma_f32_16x16x32_bf16(al, bh[p], acc[g][p], 0, 0, 0);
      }
    }
  }

  float bias[6][4];
#pragma unroll
  for (int g = 0; g < 6; ++g)
#pragma unroll
    for (int r = 0; r < 4; ++r) bias[g][r] = qb[ocbase[g] + quad * 4 + r];

  const size_t dbase = (size_t)(b * NH_ + w) * HW_ + hw0;

#pragma unroll
  for (int p = 0; p < 4; ++p) {
    float part = 0.f;
#pragma unroll
    for (int t = 0; t < 2; ++t)
#pragma unroll
      for (int r = 0; r < 4; ++r)
        part += (acc[t][p][r] + bias[t][r]) * (acc[2 + t][p][r] + bias[2 + t][r]);
    part += __shfl_xor(part, 16);
    part += __shfl_xor(part, 32);
    if (l < 16) dotbuf[dbase + p * 16 + l] = part * SCALE_;
  }

#pragma unroll
  for (int t = 0; t < 2; ++t) {
#pragma unroll
    for (int p = 0; p < 4; ++p) {
      floatx4 vv = acc[4 + t][p];
#pragma unroll
      for (int r = 0; r < 4; ++r) vv[r] += bias[4 + t][r];
      float* vp = vbuf + (dbase + p * 16 + m16) * HD_ + t * 16 + quad * 4;
      *(floatx4*)vp = vv;
    }
  }
}

// ---------------- K2: neighborhood softmax + A*V -> bf16 hi/lo out ---------
__global__ __launch_bounds__(256) void k_attn(
    const float* __restrict__ vbuf, const float* __restrict__ dotbuf,
    const float* __restrict__ rpb, unsigned short* __restrict__ ao_h,
    unsigned short* __restrict__ ao_l)
{
  __shared__ __align__(16) float at[KK_ * 256];
  __shared__ float rsum[256];
  const int tid  = threadIdx.x;
  const int blk  = blockIdx.x;
  const int head = blk / 392;
  const int rem  = blk % 392;
  const int b    = rem / 49;
  const int t49  = rem % 49;
  const int r0 = (t49 / 7) * 16;
  const int w0 = (t49 % 7) * 16;
  const float* dptr = dotbuf + (size_t)(b * NH_ + head) * HW_;

  {
    const int r = tid >> 4, wv = tid & 15;
    const int gh = r0 + r, gw = w0 + wv;
    float logit[KK_];
    float m = -1e30f;
#pragma unroll
    for (int i = 0; i < 7; ++i) {
      int hr = gh + i; if (hr >= H_) hr -= H_;
      const float* drow = dptr + hr * W_;
#pragma unroll
      for (int j = 0; j < 7; ++j) {
        int wc = gw + j; if (wc >= W_) wc -= W_;
        const float l = drow[wc] + rpb[head * KK_ + i * 7 + j];
        logit[i * 7 + j] = l;
        m = fmaxf(m, l);
      }
    }
    float s = 0.f;
#pragma unroll
    for (int o = 0; o < KK_; ++o) {
      const float e = __expf(logit[o] - m);
      s += e;
      at[o * 256 + tid] = e;
    }
    rsum[tid] = 1.0f / s;
  }
  __syncthreads();

  const int c4  = tid & 7;
  const int seg = tid >> 3;
  const int r   = seg >> 1;
  const int sx  = (seg & 1) * 8;
  const int gh  = r0 + r;
  const int pxb = r * 16 + sx;
  const float* vb = vbuf + (size_t)(b * NH_ + head) * HW_ * HD_ + c4 * 4;

  float4 acc[8];
#pragma unroll
  for (int xx = 0; xx < 8; ++xx) acc[xx] = make_float4(0.f, 0.f, 0.f, 0.f);

  for (int i = 0; i < 7; ++i) {
    int hr = gh + i; if (hr >= H_) hr -= H_;
    float4 win[14];
#pragma unroll
    for (int t = 0; t < 14; ++t) {
      int wc = w0 + sx + t; if (wc >= W_) wc -= W_;
      win[t] = *(const float4*)(vb + ((size_t)hr * W_ + wc) * HD_);
    }
#pragma unroll
    for (int j = 0; j < 7; ++j) {
      const float* arow = at + (i * 7 + j) * 256 + pxb;
      const float4 a0 = *(const float4*)arow;
      const float4 a1 = *(const float4*)(arow + 4);
      const float aw[8] = {a0.x, a0.y, a0.z, a0.w, a1.x, a1.y, a1.z, a1.w};
#pragma unroll
      for (int xx = 0; xx < 8; ++xx) {
        acc[xx].x = fmaf(aw[xx], win[xx + j].x, acc[xx].x);
        acc[xx].y = fmaf(aw[xx], win[xx + j].y, acc[xx].y);
        acc[xx].z = fmaf(aw[xx], win[xx + j].z, acc[xx].z);
        acc[xx].w = fmaf(aw[xx], win[xx + j].w, acc[xx].w);
      }
    }
  }

  // out: (B,HW,C) bf16 hi/lo planes, c = head*32 + c4*4 .. +3 (8B aligned)
  const size_t obase =
      ((size_t)b * HW_ + (size_t)gh * W_ + (w0 + sx)) * C_ + head * HD_ + c4 * 4;
#pragma unroll
  for (int xx = 0; xx < 8; ++xx) {
    const float rs = rsum[pxb + xx];
    const float o0 = acc[xx].x * rs, o1 = acc[xx].y * rs;
    const float o2 = acc[xx].z * rs, o3 = acc[xx].w * rs;
    const unsigned short h0 = f2bf(o0), h1 = f2bf(o1), h2 = f2bf(o2), h3 = f2bf(o3);
    ushort4 hv; hv.x = h0; hv.y = h1; hv.z = h2; hv.w = h3;
    ushort4 lv;
    lv.x = f2bf(o0 - bf2f(h0)); lv.y = f2bf(o1 - bf2f(h1));
    lv.z = f2bf(o2 - bf2f(h2)); lv.w = f2bf(o3 - bf2f(h3));
    *(ushort4*)(ao_h + obase + (size_t)xx * C_) = hv;
    *(ushort4*)(ao_l + obase + (size_t)xx * C_) = lv;
  }
}

// ---------------- K3: proj via split-bf16 MFMA + NHWC -> NCHW --------------
// Block = 64 px, 4 waves; wave w -> oc in [w*32, w*32+32). No LDS, no barrier.
__global__ __launch_bounds__(256, 2) void k_proj(
    const unsigned short* __restrict__ ao_h, const unsigned short* __restrict__ ao_l,
    const unsigned short* __restrict__ pwh, const unsigned short* __restrict__ pwl,
    const float* __restrict__ pb, float* __restrict__ out)
{
  const int tid = threadIdx.x;
  const int b   = blockIdx.x / 196;
  const int hw0 = (blockIdx.x % 196) * 64;
  const int w    = __builtin_amdgcn_readfirstlane(tid >> 6);
  const int l    = tid & 63;
  const int m16  = l & 15;
  const int quad = l >> 4;

  floatx4 acc[2][4];
#pragma unroll
  for (int t = 0; t < 2; ++t)
#pragma unroll
    for (int p = 0; p < 4; ++p) acc[t][p] = (floatx4){0.f, 0.f, 0.f, 0.f};

  const size_t pxbase = (size_t)b * HW_ + hw0;

  for (int ks = 0; ks < 4; ++ks) {
    short8 bh[4], bl[4];
#pragma unroll
    for (int p = 0; p < 4; ++p) {
      const size_t off = (pxbase + p * 16 + m16) * C_ + ks * 32 + quad * 8;
      bh[p] = *(const short8*)(ao_h + off);
      bl[p] = *(const short8*)(ao_l + off);
    }
#pragma unroll
    for (int t = 0; t < 2; ++t) {
      const size_t woff = (size_t)(w * 32 + t * 16 + m16) * C_ + ks * 32 + quad * 8;
      const short8 wah = *(const short8*)(pwh + woff);
      const short8 wal = *(const short8*)(pwl + woff);
#pragma unroll
      for (int p = 0; p < 4; ++p) {
        acc[t][p] = __builtin_amdgcn_mfma_f32_16x16x32_bf16(wah, bh[p], acc[t][p], 0, 0, 0);
        acc[t][p] = __builtin_amdgcn_mfma_f32_16x16x32_bf16(wah, bl[p], acc[t][p], 0, 0, 0);
        acc[t][p] = __builtin_amdgcn_mfma_f32_16x16x32_bf16(wal, bh[p], acc[t][p], 0, 0, 0);
      }
    }
  }

#pragma unroll
  for (int t = 0; t < 2; ++t) {
    float bias[4];
#pragma unroll
    for (int r = 0; r < 4; ++r) bias[r] = pb[w * 32 + t * 16 + quad * 4 + r];
#pragma unroll
    for (int p = 0; p < 4; ++p) {
#pragma unroll
      for (int r = 0; r < 4; ++r) {
        const int oc = w * 32 + t * 16 + quad * 4 + r;
        out[(size_t)b * C_ * HW_ + (size_t)oc * HW_ + hw0 + p * 16 + m16] =
            acc[t][p][r] + bias[r];
      }
    }
  }
}

extern "C" void kernel_launch(void* const* d_in, const int* in_sizes, int n_in,
                              void* d_out, int out_size, void* d_ws, size_t ws_size,
                              hipStream_t stream) {
  const float* x   = (const float*)d_in[0];
  const float* qw  = (const float*)d_in[1];
  const float* qb  = (const float*)d_in[2];
  const float* rpb = (const float*)d_in[3];
  const float* pw  = (const float*)d_in[4];
  const float* pb  = (const float*)d_in[5];
  float* out = (float*)d_out;

  float* vbuf = (float*)d_ws;                          // N*C fp32 (51.4 MB)
  float* dotb = vbuf + (size_t)N_ * C_;                // N*NH fp32 (1.6 MB)
  unsigned short* ao_h = (unsigned short*)(dotb + (size_t)N_ * NH_);  // N*C bf16
  unsigned short* ao_l = ao_h + (size_t)N_ * C_;       // N*C bf16
  unsigned short* wh   = ao_l + (size_t)N_ * C_;       // 384*128 bf16
  unsigned short* wl   = wh + 384 * C_;
  unsigned short* pwh  = wl + 384 * C_;                // 128*128 bf16
  unsigned short* pwl  = pwh + C_ * C_;

  hipLaunchKernelGGL(k_wt,   dim3(192), dim3(256), 0, stream, qw, pw, wh, wl, pwh, pwl);
  hipLaunchKernelGGL(k_qkv,  dim3(N_ / 64), dim3(256), 0, stream, x, wh, wl, qb, vbuf, dotb);
  hipLaunchKernelGGL(k_attn, dim3(NH_ * B_ * 49), dim3(256), 0, stream, vbuf, dotb, rpb, ao_h, ao_l);
  hipLaunchKernelGGL(k_proj, dim3(N_ / 64), dim3(256), 0, stream, ao_h, ao_l, pwh, pwl, pb, out);
}